// Round 3
// baseline (330.278 us; speedup 1.0000x reference)
//
#include <hip/hip_runtime.h>

typedef unsigned short u16;
typedef unsigned int   u32;
typedef __attribute__((ext_vector_type(8))) short bf16x8;
typedef __attribute__((ext_vector_type(4))) float f32x4;

#define SCALE 0.17677669529663687f  // 32^-0.5

__device__ __forceinline__ u16 f2bf(float f){
  u32 x = __float_as_uint(f);
  x += 0x7fffu + ((x >> 16) & 1u);   // RNE
  return (u16)(x >> 16);
}
__device__ __forceinline__ float bf2f(u16 u){
  return __uint_as_float(((u32)u) << 16);
}

// ---- ws layout (bytes) ----
// 0        : qkvw_bf16   [1536][512]            1,572,864
// 1572864  : projw_bf16  [512][512]               524,288
// 2097152  : biasT bf16  [16][64][64]             131,072
// 2228224  : scaleT bf16 [16][64][64]             131,072
// 2359296  : qkv bf16 [65536][1536] coalesced   201,326,592
// 203685888: x_bf16 [65536][512] (later reused as attn_out) 67,108,864

// ---------------- prep: weights->bf16, expand rel tables ----------------
__global__ void prep_kernel(const float* __restrict__ qkvw, const float* __restrict__ projw,
                            const float* __restrict__ table, const int* __restrict__ relidx,
                            u16* __restrict__ qkvw_b, u16* __restrict__ projw_b,
                            u16* __restrict__ biasT, u16* __restrict__ scaleT){
  int i = blockIdx.x * 256 + threadIdx.x;
  if (i < 786432) {
    qkvw_b[i] = f2bf(qkvw[i]);
  } else if (i < 1048576) {
    int j = i - 786432; projw_b[j] = f2bf(projw[j]);
  } else if (i < 1114112) {
    int j = i - 1048576; int h = j >> 12, rc = j & 4095;
    int idx = relidx[rc];
    biasT [h*4096 + rc] = f2bf(table[idx*32 + h]);
    scaleT[h*4096 + rc] = f2bf(table[idx*32 + 16 + h]);
  }
}

// ---------------- x (fp32) -> bf16 ----------------
__global__ void xconv_kernel(const float* __restrict__ x, u16* __restrict__ xb){
  size_t i = (size_t)blockIdx.x * 256 + threadIdx.x;  // one thread per 8 elems
  const float4* xp = (const float4*)x;
  float4 a = xp[2*i], b = xp[2*i+1];
  union { u16 u[8]; uint4 v; } o;
  o.u[0]=f2bf(a.x); o.u[1]=f2bf(a.y); o.u[2]=f2bf(a.z); o.u[3]=f2bf(a.w);
  o.u[4]=f2bf(b.x); o.u[5]=f2bf(b.y); o.u[6]=f2bf(b.z); o.u[7]=f2bf(b.w);
  *(uint4*)(xb + 8*i) = o.v;
}

// ============ GEMM: C[M][NC] = A_bf16[M][512] @ W_bf16[NC][512]^T ============
// BM=256, BN=256, BK=32 chunks, ring-3 LDS (96KB), 8 waves (2M x 4N),
// wave tile 128x64 (8 M-frags x 4 N-frags), 2 phases/chunk, counted vmcnt(4).
// Frag reads are contiguous 1KB b128 bursts (BK=32 -> 64B rows): conflict-free.
// EPI 0: qkv epilogue (bias, q*=SCALE, bf16 store to [M][1536])
// EPI 1: proj epilogue (bias, fp32 store to [M][512])
template<int EPI>
__global__ __launch_bounds__(512, 2) void gemm_kernel(
    const u16* __restrict__ A, const u16* __restrict__ W,
    const float* __restrict__ bias, void* __restrict__ outp, const int NT)
{
  // slot: A [256 rows][32 k] @ u16 0..8191 ; B [256 cols][32 k] @ 8192..16383
  __shared__ u16 lds[3][16384];   // 3 x 32KB = 96KB
  const int tid = threadIdx.x, lane = tid & 63, wid = tid >> 6;
  const int wave_base = tid & ~63;

  // bijective XCD swizzle (gridDim.x % 8 == 0 for both uses)
  const int cpx = gridDim.x >> 3;
  const int bid = (blockIdx.x & 7) * cpx + (blockIdx.x >> 3);
  const int mt = bid / NT, nt = bid % NT;
  const size_t m0 = (size_t)mt * 256;
  const int n0 = nt * 256;
  const int wm = wid >> 2, wn = wid & 3;  // wave tile: rows wm*128..+128, cols wn*64..+64

  const f32x4 z = {0.f, 0.f, 0.f, 0.f};
  f32x4 acc[8][4];
#pragma unroll
  for (int i = 0; i < 8; i++)
#pragma unroll
    for (int j = 0; j < 4; j++) acc[i][j] = z;

  // stage chunk ch (K cols [ch*32, ch*32+32)) into slot ch%3; A-half and B-half split
  auto stageA = [&](int ch){
    const int slot = ch % 3;
    const int kb = ch * 32;
#pragma unroll
    for (int c = 0; c < 2; ++c){
      const int t = c*512 + tid;
      const int row = t >> 2, sl = t & 3;
      const u16* ga = A + (m0 + row)*512 + kb + sl*8;
      u16* la = &lds[slot][(size_t)(c*512 + wave_base)*8];
      __builtin_amdgcn_global_load_lds((const __attribute__((address_space(1))) u32*)ga,
                                       (__attribute__((address_space(3))) u32*)la, 16, 0, 0);
    }
  };
  auto stageB = [&](int ch){
    const int slot = ch % 3;
    const int kb = ch * 32;
#pragma unroll
    for (int c = 0; c < 2; ++c){
      const int t = c*512 + tid;
      const int col = t >> 2, sl = t & 3;
      const u16* gb = W + (size_t)(n0 + col)*512 + kb + sl*8;
      u16* lb = &lds[slot][8192 + (size_t)(c*512 + wave_base)*8];
      __builtin_amdgcn_global_load_lds((const __attribute__((address_space(1))) u32*)gb,
                                       (__attribute__((address_space(3))) u32*)lb, 16, 0, 0);
    }
  };

  // prologue: chunks 0,1 in flight (8 loads); wait chunk 0 (vmcnt 4), keep chunk 1 flying
  stageA(0); stageB(0);
  stageA(1); stageB(1);
  asm volatile("s_waitcnt vmcnt(4)" ::: "memory");
  __builtin_amdgcn_s_barrier();

#pragma unroll
  for (int ch = 0; ch < 16; ++ch){
    const int slot = ch % 3;
    const u16* As = &lds[slot][0];
    const u16* Bs = &lds[slot][8192];
    bf16x8 af[4], bfr[4], af2[4];

    // ---- phase 0: lower 64 rows of wave tile ----
#pragma unroll
    for (int i = 0; i < 4; ++i){
      af[i]  = *(const bf16x8*)&As[(wm*128 + i*16 + (lane&15))*32 + ((lane>>4)<<3)];
      bfr[i] = *(const bf16x8*)&Bs[(wn*64  + i*16 + (lane&15))*32 + ((lane>>4)<<3)];
    }
    if (ch + 2 < 16) stageA(ch + 2);
    __builtin_amdgcn_s_barrier();
    asm volatile("s_waitcnt lgkmcnt(0)" ::: "memory");
    __builtin_amdgcn_sched_barrier(0);
    __builtin_amdgcn_s_setprio(1);
#pragma unroll
    for (int i = 0; i < 4; ++i)
#pragma unroll
      for (int j = 0; j < 4; ++j)
        acc[i][j] = __builtin_amdgcn_mfma_f32_16x16x32_bf16(af[i], bfr[j], acc[i][j], 0, 0, 0);
    __builtin_amdgcn_s_setprio(0);
    __builtin_amdgcn_s_barrier();

    // ---- phase 1: upper 64 rows (B-frags reused from phase 0) ----
#pragma unroll
    for (int i = 0; i < 4; ++i)
      af2[i] = *(const bf16x8*)&As[(wm*128 + 64 + i*16 + (lane&15))*32 + ((lane>>4)<<3)];
    if (ch + 2 < 16) stageB(ch + 2);
    __builtin_amdgcn_s_barrier();
    asm volatile("s_waitcnt lgkmcnt(0)" ::: "memory");
    __builtin_amdgcn_sched_barrier(0);
    __builtin_amdgcn_s_setprio(1);
#pragma unroll
    for (int i = 0; i < 4; ++i)
#pragma unroll
      for (int j = 0; j < 4; ++j)
        acc[4+i][j] = __builtin_amdgcn_mfma_f32_16x16x32_bf16(af2[i], bfr[j], acc[4+i][j], 0, 0, 0);
    __builtin_amdgcn_s_setprio(0);
    if (ch < 14)       { asm volatile("s_waitcnt vmcnt(4)" ::: "memory"); }
    else if (ch == 14) { asm volatile("s_waitcnt vmcnt(0)" ::: "memory"); }
    if (ch < 15) __builtin_amdgcn_s_barrier();
  }

  // epilogue (coalesced linear stores)
  const int lr = (lane >> 4) << 2;
  const int lc = lane & 15;
  if (EPI == 0){
    u16* o = (u16*)outp;
#pragma unroll
    for (int nf = 0; nf < 4; ++nf){
      const int col = n0 + wn*64 + nf*16 + lc;
      const float bv = bias[col];
      const float sc = (col < 512) ? SCALE : 1.f;
#pragma unroll
      for (int mf = 0; mf < 8; ++mf){
#pragma unroll
        for (int r = 0; r < 4; ++r){
          const size_t row = m0 + wm*128 + mf*16 + lr + r;
          o[row*1536 + col] = f2bf((acc[mf][nf][r] + bv) * sc);
        }
      }
    }
  } else {
    float* o = (float*)outp;
#pragma unroll
    for (int nf = 0; nf < 4; ++nf){
      const int col = n0 + wn*64 + nf*16 + lc;
      const float bv = bias[col];
#pragma unroll
      for (int mf = 0; mf < 8; ++mf){
#pragma unroll
        for (int r = 0; r < 4; ++r){
          const size_t row = m0 + wm*128 + mf*16 + lr + r;
          o[row*512 + col] = acc[mf][nf][r] + bv;
        }
      }
    }
  }
}

// ---------------- attention: one block per (b,h), qkv in [M][1536] ----------------
__global__ __launch_bounds__(256) void attn_kernel(
    const u16* __restrict__ qkv, const u16* __restrict__ biasT,
    const u16* __restrict__ scaleT, u16* __restrict__ attn_out)
{
  __shared__ u16 qs[64*40];   // [64][32] pad->40 elems
  __shared__ u16 ks[64*40];
  __shared__ u16 vs[64*40];
  __shared__ u16 Ps[64*72];   // [64][64] pad->72
  const int tid = threadIdx.x, lane = tid & 63, wid = tid >> 6;
  const int bh = blockIdx.x, b = bh >> 4, h = bh & 15;
  const u16* base = qkv + (size_t)b * 64 * 1536 + h * 32;
  {
    const int row = tid >> 2, seg = (tid & 3) * 8;
    const size_t ro = (size_t)row * 1536 + seg;
    *(uint4*)&qs[row*40 + seg] = *(const uint4*)(base + ro);
    *(uint4*)&ks[row*40 + seg] = *(const uint4*)(base + ro + 512);
    *(uint4*)&vs[row*40 + seg] = *(const uint4*)(base + ro + 1024);
  }
  __syncthreads();

  const int wr0 = wid * 16;
  const int lg = lane >> 4, lc = lane & 15;
  const f32x4 z = {0.f, 0.f, 0.f, 0.f};

  // S = q @ k^T  (q pre-scaled in GEMM epilogue)
  bf16x8 qf = *(const bf16x8*)&qs[(wr0 + lc)*40 + lg*8];
  f32x4 s[4];
#pragma unroll
  for (int ct = 0; ct < 4; ++ct){
    bf16x8 kf = *(const bf16x8*)&ks[(ct*16 + lc)*40 + lg*8];
    s[ct] = __builtin_amdgcn_mfma_f32_16x16x32_bf16(qf, kf, z, 0, 0, 0);
  }

  const u16* bT = biasT + h*4096;
  const u16* sT = scaleT + h*4096;
#pragma unroll
  for (int r = 0; r < 4; ++r){
    const int row = wr0 + lg*4 + r;
    float vals[4]; float mx = -1e30f;
#pragma unroll
    for (int ct = 0; ct < 4; ++ct){
      vals[ct] = s[ct][r] + bf2f(bT[row*64 + ct*16 + lc]);
      mx = fmaxf(mx, vals[ct]);
    }
    mx = fmaxf(mx, __shfl_xor(mx, 1));
    mx = fmaxf(mx, __shfl_xor(mx, 2));
    mx = fmaxf(mx, __shfl_xor(mx, 4));
    mx = fmaxf(mx, __shfl_xor(mx, 8));
    float sm = 0.f;
#pragma unroll
    for (int ct = 0; ct < 4; ++ct){ vals[ct] = __expf(vals[ct] - mx); sm += vals[ct]; }
    sm += __shfl_xor(sm, 1);
    sm += __shfl_xor(sm, 2);
    sm += __shfl_xor(sm, 4);
    sm += __shfl_xor(sm, 8);
    const float inv = 1.f / sm;
#pragma unroll
    for (int ct = 0; ct < 4; ++ct){
      const int col = ct*16 + lc;
      Ps[row*72 + col] = f2bf(vals[ct] * inv * bf2f(sT[row*64 + col]));
    }
  }
  __syncthreads();

  // out = P @ V
  f32x4 o[2] = {z, z};
#pragma unroll
  for (int kc = 0; kc < 2; ++kc){
    bf16x8 pf = *(const bf16x8*)&Ps[(wr0 + lc)*72 + kc*32 + lg*8];
#pragma unroll
    for (int c2 = 0; c2 < 2; ++c2){
      union { u16 u[8]; bf16x8 v; } vf;
#pragma unroll
      for (int e = 0; e < 8; ++e)
        vf.u[e] = vs[(kc*32 + lg*8 + e)*40 + c2*16 + lc];
      o[c2] = __builtin_amdgcn_mfma_f32_16x16x32_bf16(pf, vf.v, o[c2], 0, 0, 0);
    }
  }

#pragma unroll
  for (int c2 = 0; c2 < 2; ++c2){
#pragma unroll
    for (int r = 0; r < 4; ++r){
      const int n = wr0 + lg*4 + r;
      attn_out[((size_t)b*64 + n)*512 + h*32 + c2*16 + lc] = f2bf(o[c2][r]);
    }
  }
}

extern "C" void kernel_launch(void* const* d_in, const int* in_sizes, int n_in,
                              void* d_out, int out_size, void* d_ws, size_t ws_size,
                              hipStream_t stream)
{
  const float* x      = (const float*)d_in[0];
  const float* qkvw   = (const float*)d_in[1];
  const float* qkvb   = (const float*)d_in[2];
  const float* projw  = (const float*)d_in[3];
  const float* projb  = (const float*)d_in[4];
  const float* table  = (const float*)d_in[5];
  const int*   relidx = (const int*)d_in[6];
  char* ws = (char*)d_ws;

  u16* qkvw_b = (u16*)(ws + 0);
  u16* projw_b= (u16*)(ws + 1572864);
  u16* biasT  = (u16*)(ws + 2097152);
  u16* scaleT = (u16*)(ws + 2228224);
  u16* qkvws  = (u16*)(ws + 2359296);      // [65536][1536] bf16
  u16* xb     = (u16*)(ws + 203685888);    // reused as attn_out after qkv GEMM
  u16* attn_o = xb;

  if (ws_size < 270794752ull) return;

  prep_kernel<<<dim3(4352), dim3(256), 0, stream>>>(qkvw, projw, table, relidx,
                                                    qkvw_b, projw_b, biasT, scaleT);
  xconv_kernel<<<dim3(16384), dim3(256), 0, stream>>>(x, xb);
  gemm_kernel<0><<<dim3(1536), dim3(512), 0, stream>>>(xb, qkvw_b, qkvb, (void*)qkvws, 6);
  attn_kernel<<<dim3(16384), dim3(256), 0, stream>>>(qkvws, biasT, scaleT, attn_o);
  gemm_kernel<1><<<dim3(512), dim3(512), 0, stream>>>(attn_o, projw_b, projb, d_out, 2);
}

// Round 4
// 287.073 us; speedup vs baseline: 1.1505x; 1.1505x over previous
//
#include <hip/hip_runtime.h>

typedef unsigned short u16;
typedef unsigned int   u32;
typedef __attribute__((ext_vector_type(8))) short bf16x8;
typedef __attribute__((ext_vector_type(4))) float f32x4;

#define SCALE 0.17677669529663687f  // 32^-0.5

__device__ __forceinline__ u16 f2bf(float f){
  u32 x = __float_as_uint(f);
  x += 0x7fffu + ((x >> 16) & 1u);   // RNE
  return (u16)(x >> 16);
}
__device__ __forceinline__ float bf2f(u16 u){
  return __uint_as_float(((u32)u) << 16);
}

// ---- ws layout (bytes) ----
// 0        : qkvw_bf16   [1536][512]            1,572,864
// 1572864  : projw_bf16  [512][512]               524,288
// 2097152  : biasT bf16  [16][64][64]             131,072
// 2228224  : scaleT bf16 [16][64][64]             131,072
// 2359296  : qkv bf16 [65536][1536] coalesced   201,326,592
// 203685888: x_bf16 [65536][512] (later reused as attn_out) 67,108,864

// ---------------- prep: weights->bf16, expand rel tables ----------------
__global__ void prep_kernel(const float* __restrict__ qkvw, const float* __restrict__ projw,
                            const float* __restrict__ table, const int* __restrict__ relidx,
                            u16* __restrict__ qkvw_b, u16* __restrict__ projw_b,
                            u16* __restrict__ biasT, u16* __restrict__ scaleT){
  int i = blockIdx.x * 256 + threadIdx.x;
  if (i < 786432) {
    qkvw_b[i] = f2bf(qkvw[i]);
  } else if (i < 1048576) {
    int j = i - 786432; projw_b[j] = f2bf(projw[j]);
  } else if (i < 1114112) {
    int j = i - 1048576; int h = j >> 12, rc = j & 4095;
    int idx = relidx[rc];
    biasT [h*4096 + rc] = f2bf(table[idx*32 + h]);
    scaleT[h*4096 + rc] = f2bf(table[idx*32 + 16 + h]);
  }
}

// ---------------- x (fp32) -> bf16 ----------------
__global__ void xconv_kernel(const float* __restrict__ x, u16* __restrict__ xb){
  size_t i = (size_t)blockIdx.x * 256 + threadIdx.x;  // one thread per 8 elems
  const float4* xp = (const float4*)x;
  float4 a = xp[2*i], b = xp[2*i+1];
  union { u16 u[8]; uint4 v; } o;
  o.u[0]=f2bf(a.x); o.u[1]=f2bf(a.y); o.u[2]=f2bf(a.z); o.u[3]=f2bf(a.w);
  o.u[4]=f2bf(b.x); o.u[5]=f2bf(b.y); o.u[6]=f2bf(b.z); o.u[7]=f2bf(b.w);
  *(uint4*)(xb + 8*i) = o.v;
}

// ============ GEMM: C[M][NC] = A_bf16[M][512] @ W_bf16[NC][512]^T ============
// BM=256, BN=256, BK=32 chunks, ring-3 LDS (96KB), 8 waves (2M x 4N),
// wave tile 128x64 (8 M-frags x 4 N-frags), 2 phases/chunk, counted vmcnt(4).
// LDS swizzle: 64-B rows of 4 16B-slots; phys slot p of row r holds logical
// k-slot p ^ ((r>>1)&3). Applied on global SOURCE (linear LDS dest, rule #21)
// and on the ds_read address. Wave64 b128 frag read -> exactly 2 lanes/bank.
// EPI 0: qkv epilogue (bias, q*=SCALE, bf16 store to [M][1536])
// EPI 1: proj epilogue (bias, fp32 store to [M][512])
template<int EPI>
__global__ __launch_bounds__(512, 2) void gemm_kernel(
    const u16* __restrict__ A, const u16* __restrict__ W,
    const float* __restrict__ bias, void* __restrict__ outp, const int NT)
{
  // slot: A [256 rows][32 k] @ u16 0..8191 ; B [256 cols][32 k] @ 8192..16383
  __shared__ u16 lds[3][16384];   // 3 x 32KB = 96KB
  const int tid = threadIdx.x, lane = tid & 63, wid = tid >> 6;
  const int wave_base = tid & ~63;

  // bijective XCD swizzle (gridDim.x % 8 == 0 for both uses)
  const int cpx = gridDim.x >> 3;
  const int bid = (blockIdx.x & 7) * cpx + (blockIdx.x >> 3);
  const int mt = bid / NT, nt = bid % NT;
  const size_t m0 = (size_t)mt * 256;
  const int n0 = nt * 256;
  const int wm = wid >> 2, wn = wid & 3;  // wave tile: rows wm*128..+128, cols wn*64..+64

  const f32x4 z = {0.f, 0.f, 0.f, 0.f};
  f32x4 acc[8][4];
#pragma unroll
  for (int i = 0; i < 8; i++)
#pragma unroll
    for (int j = 0; j < 4; j++) acc[i][j] = z;

  // stage chunk ch (K cols [ch*32, ch*32+32)) into slot ch%3.
  // linear LDS dest; global source pre-swizzled: phys slot sl holds logical sl^((row>>1)&3)
  auto stageA = [&](int ch){
    const int slot = ch % 3;
    const int kb = ch * 32;
#pragma unroll
    for (int c = 0; c < 2; ++c){
      const int t = c*512 + tid;
      const int row = t >> 2, sl = t & 3;
      const int lsl = sl ^ ((row >> 1) & 3);
      const u16* ga = A + (m0 + row)*512 + kb + lsl*8;
      u16* la = &lds[slot][(size_t)(c*512 + wave_base)*8];
      __builtin_amdgcn_global_load_lds((const __attribute__((address_space(1))) u32*)ga,
                                       (__attribute__((address_space(3))) u32*)la, 16, 0, 0);
    }
  };
  auto stageB = [&](int ch){
    const int slot = ch % 3;
    const int kb = ch * 32;
#pragma unroll
    for (int c = 0; c < 2; ++c){
      const int t = c*512 + tid;
      const int col = t >> 2, sl = t & 3;
      const int lsl = sl ^ ((col >> 1) & 3);
      const u16* gb = W + (size_t)(n0 + col)*512 + kb + lsl*8;
      u16* lb = &lds[slot][8192 + (size_t)(c*512 + wave_base)*8];
      __builtin_amdgcn_global_load_lds((const __attribute__((address_space(1))) u32*)gb,
                                       (__attribute__((address_space(3))) u32*)lb, 16, 0, 0);
    }
  };

  // prologue: chunks 0,1 in flight (8 calls); wait chunk 0 (vmcnt 4), keep chunk 1 flying
  stageA(0); stageB(0);
  stageA(1); stageB(1);
  asm volatile("s_waitcnt vmcnt(4)" ::: "memory");
  __builtin_amdgcn_s_barrier();

  const int lq = lane & 15, lk = lane >> 4;
#pragma unroll
  for (int ch = 0; ch < 16; ++ch){
    const int slot = ch % 3;
    const u16* As = &lds[slot][0];
    const u16* Bs = &lds[slot][8192];
    bf16x8 af[4], bfr[4], af2[4];

    // ---- phase 0: lower 64 rows of wave tile (+ all B frags) ----
#pragma unroll
    for (int i = 0; i < 4; ++i){
      const int row = wm*128 + i*16 + lq;
      af[i]  = *(const bf16x8*)&As[row*32 + (lk ^ ((row >> 1) & 3))*8];
      const int col = wn*64 + i*16 + lq;
      bfr[i] = *(const bf16x8*)&Bs[col*32 + (lk ^ ((col >> 1) & 3))*8];
    }
    if (ch + 2 < 16) stageA(ch + 2);
    __builtin_amdgcn_s_barrier();
    asm volatile("s_waitcnt lgkmcnt(0)" ::: "memory");
    __builtin_amdgcn_sched_barrier(0);
    __builtin_amdgcn_s_setprio(1);
#pragma unroll
    for (int i = 0; i < 4; ++i)
#pragma unroll
      for (int j = 0; j < 4; ++j)
        acc[i][j] = __builtin_amdgcn_mfma_f32_16x16x32_bf16(af[i], bfr[j], acc[i][j], 0, 0, 0);
    __builtin_amdgcn_s_setprio(0);
    __builtin_amdgcn_s_barrier();

    // ---- phase 1: upper 64 rows (B-frags reused from phase 0) ----
#pragma unroll
    for (int i = 0; i < 4; ++i){
      const int row = wm*128 + 64 + i*16 + lq;
      af2[i] = *(const bf16x8*)&As[row*32 + (lk ^ ((row >> 1) & 3))*8];
    }
    if (ch + 2 < 16) stageB(ch + 2);
    __builtin_amdgcn_s_barrier();
    asm volatile("s_waitcnt lgkmcnt(0)" ::: "memory");
    __builtin_amdgcn_sched_barrier(0);
    __builtin_amdgcn_s_setprio(1);
#pragma unroll
    for (int i = 0; i < 4; ++i)
#pragma unroll
      for (int j = 0; j < 4; ++j)
        acc[4+i][j] = __builtin_amdgcn_mfma_f32_16x16x32_bf16(af2[i], bfr[j], acc[4+i][j], 0, 0, 0);
    __builtin_amdgcn_s_setprio(0);
    if (ch < 14)       { asm volatile("s_waitcnt vmcnt(4)" ::: "memory"); }
    else if (ch == 14) { asm volatile("s_waitcnt vmcnt(0)" ::: "memory"); }
    if (ch < 15) __builtin_amdgcn_s_barrier();
  }

  // epilogue — nf INNERMOST so each wave completes its 128-B line in 4
  // consecutive stores (avoids partial-line L2 eviction -> write amplification)
  const int lr = (lane >> 4) << 2;
  const int lc = lane & 15;
  if (EPI == 0){
    u16* o = (u16*)outp;
    float bv[4], sc[4];
#pragma unroll
    for (int nf = 0; nf < 4; ++nf){
      const int col = n0 + wn*64 + nf*16 + lc;
      bv[nf] = bias[col];
      sc[nf] = (col < 512) ? SCALE : 1.f;
    }
#pragma unroll
    for (int mf = 0; mf < 8; ++mf){
#pragma unroll
      for (int r = 0; r < 4; ++r){
        const size_t row = m0 + wm*128 + mf*16 + lr + r;
#pragma unroll
        for (int nf = 0; nf < 4; ++nf){
          const int col = n0 + wn*64 + nf*16 + lc;
          o[row*1536 + col] = f2bf((acc[mf][nf][r] + bv[nf]) * sc[nf]);
        }
      }
    }
  } else {
    float* o = (float*)outp;
    float bv[4];
#pragma unroll
    for (int nf = 0; nf < 4; ++nf)
      bv[nf] = bias[n0 + wn*64 + nf*16 + lc];
#pragma unroll
    for (int mf = 0; mf < 8; ++mf){
#pragma unroll
      for (int r = 0; r < 4; ++r){
        const size_t row = m0 + wm*128 + mf*16 + lr + r;
#pragma unroll
        for (int nf = 0; nf < 4; ++nf){
          const int col = n0 + wn*64 + nf*16 + lc;
          o[row*512 + col] = acc[mf][nf][r] + bv[nf];
        }
      }
    }
  }
}

// ---------------- attention: one block per (b,h), qkv in [M][1536] ----------------
__global__ __launch_bounds__(256) void attn_kernel(
    const u16* __restrict__ qkv, const u16* __restrict__ biasT,
    const u16* __restrict__ scaleT, u16* __restrict__ attn_out)
{
  __shared__ u16 qs[64*40];   // [64][32] pad->40 elems
  __shared__ u16 ks[64*40];
  __shared__ u16 vs[64*40];
  __shared__ u16 Ps[64*72];   // [64][64] pad->72
  const int tid = threadIdx.x, lane = tid & 63, wid = tid >> 6;
  const int bh = blockIdx.x, b = bh >> 4, h = bh & 15;
  const u16* base = qkv + (size_t)b * 64 * 1536 + h * 32;
  {
    const int row = tid >> 2, seg = (tid & 3) * 8;
    const size_t ro = (size_t)row * 1536 + seg;
    *(uint4*)&qs[row*40 + seg] = *(const uint4*)(base + ro);
    *(uint4*)&ks[row*40 + seg] = *(const uint4*)(base + ro + 512);
    *(uint4*)&vs[row*40 + seg] = *(const uint4*)(base + ro + 1024);
  }
  __syncthreads();

  const int wr0 = wid * 16;
  const int lg = lane >> 4, lc = lane & 15;
  const f32x4 z = {0.f, 0.f, 0.f, 0.f};

  // S = q @ k^T  (q pre-scaled in GEMM epilogue)
  bf16x8 qf = *(const bf16x8*)&qs[(wr0 + lc)*40 + lg*8];
  f32x4 s[4];
#pragma unroll
  for (int ct = 0; ct < 4; ++ct){
    bf16x8 kf = *(const bf16x8*)&ks[(ct*16 + lc)*40 + lg*8];
    s[ct] = __builtin_amdgcn_mfma_f32_16x16x32_bf16(qf, kf, z, 0, 0, 0);
  }

  const u16* bT = biasT + h*4096;
  const u16* sT = scaleT + h*4096;
#pragma unroll
  for (int r = 0; r < 4; ++r){
    const int row = wr0 + lg*4 + r;
    float vals[4]; float mx = -1e30f;
#pragma unroll
    for (int ct = 0; ct < 4; ++ct){
      vals[ct] = s[ct][r] + bf2f(bT[row*64 + ct*16 + lc]);
      mx = fmaxf(mx, vals[ct]);
    }
    mx = fmaxf(mx, __shfl_xor(mx, 1));
    mx = fmaxf(mx, __shfl_xor(mx, 2));
    mx = fmaxf(mx, __shfl_xor(mx, 4));
    mx = fmaxf(mx, __shfl_xor(mx, 8));
    float sm = 0.f;
#pragma unroll
    for (int ct = 0; ct < 4; ++ct){ vals[ct] = __expf(vals[ct] - mx); sm += vals[ct]; }
    sm += __shfl_xor(sm, 1);
    sm += __shfl_xor(sm, 2);
    sm += __shfl_xor(sm, 4);
    sm += __shfl_xor(sm, 8);
    const float inv = 1.f / sm;
#pragma unroll
    for (int ct = 0; ct < 4; ++ct){
      const int col = ct*16 + lc;
      Ps[row*72 + col] = f2bf(vals[ct] * inv * bf2f(sT[row*64 + col]));
    }
  }
  __syncthreads();

  // out = P @ V
  f32x4 o[2] = {z, z};
#pragma unroll
  for (int kc = 0; kc < 2; ++kc){
    bf16x8 pf = *(const bf16x8*)&Ps[(wr0 + lc)*72 + kc*32 + lg*8];
#pragma unroll
    for (int c2 = 0; c2 < 2; ++c2){
      union { u16 u[8]; bf16x8 v; } vf;
#pragma unroll
      for (int e = 0; e < 8; ++e)
        vf.u[e] = vs[(kc*32 + lg*8 + e)*40 + c2*16 + lc];
      o[c2] = __builtin_amdgcn_mfma_f32_16x16x32_bf16(pf, vf.v, o[c2], 0, 0, 0);
    }
  }

#pragma unroll
  for (int c2 = 0; c2 < 2; ++c2){
#pragma unroll
    for (int r = 0; r < 4; ++r){
      const int n = wr0 + lg*4 + r;
      attn_out[((size_t)b*64 + n)*512 + h*32 + c2*16 + lc] = f2bf(o[c2][r]);
    }
  }
}

extern "C" void kernel_launch(void* const* d_in, const int* in_sizes, int n_in,
                              void* d_out, int out_size, void* d_ws, size_t ws_size,
                              hipStream_t stream)
{
  const float* x      = (const float*)d_in[0];
  const float* qkvw   = (const float*)d_in[1];
  const float* qkvb   = (const float*)d_in[2];
  const float* projw  = (const float*)d_in[3];
  const float* projb  = (const float*)d_in[4];
  const float* table  = (const float*)d_in[5];
  const int*   relidx = (const int*)d_in[6];
  char* ws = (char*)d_ws;

  u16* qkvw_b = (u16*)(ws + 0);
  u16* projw_b= (u16*)(ws + 1572864);
  u16* biasT  = (u16*)(ws + 2097152);
  u16* scaleT = (u16*)(ws + 2228224);
  u16* qkvws  = (u16*)(ws + 2359296);      // [65536][1536] bf16
  u16* xb     = (u16*)(ws + 203685888);    // reused as attn_out after qkv GEMM
  u16* attn_o = xb;

  if (ws_size < 270794752ull) return;

  prep_kernel<<<dim3(4352), dim3(256), 0, stream>>>(qkvw, projw, table, relidx,
                                                    qkvw_b, projw_b, biasT, scaleT);
  xconv_kernel<<<dim3(16384), dim3(256), 0, stream>>>(x, xb);
  gemm_kernel<0><<<dim3(1536), dim3(512), 0, stream>>>(xb, qkvw_b, qkvb, (void*)qkvws, 6);
  attn_kernel<<<dim3(16384), dim3(256), 0, stream>>>(qkvws, biasT, scaleT, attn_o);
  gemm_kernel<1><<<dim3(512), dim3(512), 0, stream>>>(attn_o, projw_b, projb, d_out, 2);
}